// Round 1
// baseline (12791.996 us; speedup 1.0000x reference)
//
#include <hip/hip_runtime.h>
#include <stdint.h>
#include <stddef.h>

// ===================== problem constants =====================
#define LT    2048
#define BATCH 64
#define NH    256
#define HS_ELEMS  (BATCH * LT * NH)   // 33554432
#define OUT_ELEMS (BATCH * LT * 2)    // 262144
// d_out layout: [hs (B,L,256) | outs (B,L,2) | priors (B,L,16)] fp32

typedef __attribute__((ext_vector_type(8))) __bf16 bf16x8;
typedef __attribute__((ext_vector_type(4))) float  f32x4;

static __device__ __forceinline__ unsigned short f2bf_bits(float f) {
  unsigned u = __builtin_bit_cast(unsigned, f);
  u = (u + 0x7FFFu + ((u >> 16) & 1u)) >> 16;   // RNE
  return (unsigned short)u;
}
static __device__ __forceinline__ __bf16 f2bf(float f) {
  unsigned short s = f2bf_bits(f);
  return __builtin_bit_cast(__bf16, s);
}
static __device__ __forceinline__ unsigned packbf2(float a, float b) {
  return (unsigned)f2bf_bits(a) | ((unsigned)f2bf_bits(b) << 16);
}
// XOR swizzle: flips byte-address bits 4..6 within a row -> 2-way max bank alias
static __device__ __forceinline__ int swz(int row, int byteoff) {
  return byteoff ^ ((row & 7) << 4);
}

// LDS layout (bytes) for the serial kernel
#define W_RES_OFF 0        // 256 rows x 512B  (W_res[n][k] bf16, swizzled)
#define A_S_OFF   131072   // 16 rows x 1024B  (h bf16 at [0,512), r at [512,1024))
#define W_PR_OFF  147456   // 16 rows x 512B   (W_pr[n][k] bf16, swizzled)
#define LDS_BYTES 155648

// ===================== kernel 1: u = x @ W_in^T + (b_in+b_hh+b_sf) ==========
// writes u into the hs region of d_out; serial kernel reads it as acc-init and
// overwrites each slot with h afterwards (same thread does read then write).
__global__ __launch_bounds__(256) void u_precompute_kernel(
    const float* __restrict__ x,      // [B, L, 16]
    const float* __restrict__ W_in,   // [256, 16]
    const float* __restrict__ b_in,
    const float* __restrict__ b_hh,
    const float* __restrict__ b_sf,
    float* __restrict__ u)            // [B, L, 256] (= hs region)
{
  __shared__ float xs[64][16];
  const int tid = threadIdx.x;
  const int b  = blockIdx.x >> 5;
  const int tc = (blockIdx.x & 31) << 6;   // 64 timesteps per block
  float w[16];
#pragma unroll
  for (int i = 0; i < 16; ++i) w[i] = W_in[tid * 16 + i];
  const float bias = b_in[tid] + b_hh[tid] + b_sf[tid];
  for (int r = tid; r < 64 * 16; r += 256)
    xs[r >> 4][r & 15] = x[((size_t)b * LT + tc + (r >> 4)) * 16 + (r & 15)];
  __syncthreads();
  for (int tt = 0; tt < 64; ++tt) {
    float s = bias;
#pragma unroll
    for (int i = 0; i < 16; ++i) s += xs[tt][i] * w[i];
    u[((size_t)b * LT + tc + tt) * NH + tid] = s;
  }
}

// ===================== kernel 2: the serial recurrence =====================
// 4 WGs x 256 threads (4 waves, 1 wave/SIMD, up to 512 VGPRs).
// Each WG owns 16 batch rows. Per step:
//   tmp_h = relu(u_t + h@W_hh^T + r@W_sf^T)        -> h = tmp_h + noise  (af=1)
//   tmp_r = relu(h@W_fs^T + r@W_res^T + b_fs+b_res) -> r = 0.9r + 0.1tmp_r
// MFMA 16x16x32 bf16, M=16 batch. Wave w owns output cols n in [64w, 64w+64)
// as 4 tiles of 16 for both tmp_h and tmp_r. W_hh/W_sf/W_fs fragments live in
// VGPRs; W_res streams from LDS. prior (needs r) computed by wave 1, deferred
// one step. K-element order is consistent across A-frags/B-frags/reg packing,
// so the HW k-permutation cancels in the dot product.
__global__ __launch_bounds__(256, 1) void rnn_seq_kernel(
    const float* __restrict__ hidden,     // [B,256]
    const float* __restrict__ reservoir,  // [B,256]
    const float* __restrict__ noise,      // [L,B,256]
    const float* __restrict__ W_hh, const float* __restrict__ W_sf,
    const float* __restrict__ W_fs, const float* __restrict__ W_res,
    const float* __restrict__ b_fs, const float* __restrict__ b_res,
    const float* __restrict__ W_pr, const float* __restrict__ b_pr,
    float* __restrict__ hs,               // [B,L,256] (holds u on entry)
    float* __restrict__ priors)           // [B,L,16]
{
  extern __shared__ char lds[];
  const int tid  = threadIdx.x;
  const int lane = tid & 63;
  const int wv   = tid >> 6;        // wave 0..3
  const int col  = lane & 15;       // N-index within tile / A row (m)
  const int kg   = lane >> 4;       // k-group 0..3
  const int b0   = blockIdx.x * 16;

  // ---- stage W_res into LDS: [n][k] bf16, row-swizzled ----
  {
    const int n = tid;
    const float* src = W_res + (size_t)n * NH;
    char* row = lds + W_RES_OFF + n * 512;
#pragma unroll 4
    for (int k = 0; k < NH; k += 4) {
      *(unsigned*)(row + swz(n, k * 2))     = packbf2(src[k],     src[k + 1]);
      *(unsigned*)(row + swz(n, k * 2 + 4)) = packbf2(src[k + 2], src[k + 3]);
    }
  }
  // ---- stage W_pr (16 rows) ----
  {
    const int n = tid >> 4, seg = tid & 15;      // 16 elems per thread
    const float* src = W_pr + (size_t)n * NH + seg * 16;
    char* row = lds + W_PR_OFF + n * 512;
#pragma unroll
    for (int i = 0; i < 16; i += 2)
      *(unsigned*)(row + swz(n, (seg * 16 + i) * 2)) = packbf2(src[i], src[i + 1]);
  }
  // ---- stage initial state h0, r0 into A_s ----
  {
    const int m = tid >> 4, seg = tid & 15;
    const float* hsrc = hidden    + (size_t)(b0 + m) * NH + seg * 16;
    const float* rsrc = reservoir + (size_t)(b0 + m) * NH + seg * 16;
    char* row = lds + A_S_OFF + m * 1024;
#pragma unroll
    for (int i = 0; i < 16; i += 2) {
      *(unsigned*)(row + swz(m, (seg * 16 + i) * 2))       = packbf2(hsrc[i], hsrc[i + 1]);
      *(unsigned*)(row + swz(m, 512 + (seg * 16 + i) * 2)) = packbf2(rsrc[i], rsrc[i + 1]);
    }
  }

  // ---- per-lane weight fragments in registers ----
  bf16x8 wHH[4][8], wSF[4][8], wFS[4][8];
  float biasr[4];
#pragma unroll
  for (int tile = 0; tile < 4; ++tile) {
    const int n = wv * 64 + tile * 16 + col;
    const float* ph = W_hh + (size_t)n * NH + kg * 8;
    const float* ps = W_sf + (size_t)n * NH + kg * 8;
    const float* pf = W_fs + (size_t)n * NH + kg * 8;
#pragma unroll
    for (int kk = 0; kk < 8; ++kk) {
      f32x4 lo, hi; bf16x8 f;
      lo = *(const f32x4*)(ph + kk * 32); hi = *(const f32x4*)(ph + kk * 32 + 4);
      f[0]=f2bf(lo[0]); f[1]=f2bf(lo[1]); f[2]=f2bf(lo[2]); f[3]=f2bf(lo[3]);
      f[4]=f2bf(hi[0]); f[5]=f2bf(hi[1]); f[6]=f2bf(hi[2]); f[7]=f2bf(hi[3]);
      wHH[tile][kk] = f;
      lo = *(const f32x4*)(ps + kk * 32); hi = *(const f32x4*)(ps + kk * 32 + 4);
      f[0]=f2bf(lo[0]); f[1]=f2bf(lo[1]); f[2]=f2bf(lo[2]); f[3]=f2bf(lo[3]);
      f[4]=f2bf(hi[0]); f[5]=f2bf(hi[1]); f[6]=f2bf(hi[2]); f[7]=f2bf(hi[3]);
      wSF[tile][kk] = f;
      lo = *(const f32x4*)(pf + kk * 32); hi = *(const f32x4*)(pf + kk * 32 + 4);
      f[0]=f2bf(lo[0]); f[1]=f2bf(lo[1]); f[2]=f2bf(lo[2]); f[3]=f2bf(lo[3]);
      f[4]=f2bf(hi[0]); f[5]=f2bf(hi[1]); f[6]=f2bf(hi[2]); f[7]=f2bf(hi[3]);
      wFS[tile][kk] = f;
    }
    biasr[tile] = b_fs[n] + b_res[n];
  }
  const float bpP = b_pr[col];

  // r state in fp32 registers (D-layout: row m = kg*4+j, col n per tile)
  float r_old[4][4];
#pragma unroll
  for (int tile = 0; tile < 4; ++tile) {
    const int n = wv * 64 + tile * 16 + col;
#pragma unroll
    for (int j = 0; j < 4; ++j)
      r_old[tile][j] = reservoir[(size_t)(b0 + kg * 4 + j) * NH + n];
  }

  // accumulators: accH pre-initialized with u(0); accR with biases
  f32x4 accH[4], accR[4], accP;
  float nz[4][4];
#pragma unroll
  for (int tile = 0; tile < 4; ++tile) {
    const int n = wv * 64 + tile * 16 + col;
#pragma unroll
    for (int j = 0; j < 4; ++j) {
      const int m = kg * 4 + j;
      accH[tile][j] = hs[(size_t)(b0 + m) * (LT * NH) + n];           // u(b, t=0, n)
      nz[tile][j]   = noise[(size_t)(b0 + m) * NH + n];               // noise(t=0)
      accR[tile][j] = biasr[tile];
    }
  }
#pragma unroll
  for (int j = 0; j < 4; ++j) accP[j] = bpP;

  __syncthreads();

#pragma unroll 1
  for (int t = 0; t < LT; ++t) {
    // -------- K-loop: K=512 over [h | r], 16 k-steps --------
#pragma unroll
    for (int kk = 0; kk < 16; ++kk) {
      const bf16x8 af = *(const bf16x8*)(lds + A_S_OFF + col * 1024 +
                                         swz(col, kk * 64 + kg * 16));
      if (kk < 8) {
#pragma unroll
        for (int tile = 0; tile < 4; ++tile)
          accH[tile] = __builtin_amdgcn_mfma_f32_16x16x32_bf16(af, wHH[tile][kk], accH[tile], 0, 0, 0);
#pragma unroll
        for (int tile = 0; tile < 4; ++tile)
          accR[tile] = __builtin_amdgcn_mfma_f32_16x16x32_bf16(af, wFS[tile][kk], accR[tile], 0, 0, 0);
      } else {
#pragma unroll
        for (int tile = 0; tile < 4; ++tile)
          accH[tile] = __builtin_amdgcn_mfma_f32_16x16x32_bf16(af, wSF[tile][kk - 8], accH[tile], 0, 0, 0);
#pragma unroll
        for (int tile = 0; tile < 4; ++tile) {
          const int n = wv * 64 + tile * 16 + col;
          const bf16x8 bw = *(const bf16x8*)(lds + W_RES_OFF + n * 512 +
                                             swz(n, (kk - 8) * 64 + kg * 16));
          accR[tile] = __builtin_amdgcn_mfma_f32_16x16x32_bf16(af, bw, accR[tile], 0, 0, 0);
        }
        if (wv == 1) {  // prior_{t-1} from staged r_{t-1}
          const bf16x8 bp = *(const bf16x8*)(lds + W_PR_OFF + col * 512 +
                                             swz(col, (kk - 8) * 64 + kg * 16));
          accP = __builtin_amdgcn_mfma_f32_16x16x32_bf16(af, bp, accP, 0, 0, 0);
        }
      }
    }
    __syncthreads();   // all reads of A_s done

    // -------- epilogue: update state, store h, restage A_s --------
#pragma unroll
    for (int tile = 0; tile < 4; ++tile) {
      const int n = wv * 64 + tile * 16 + col;
#pragma unroll
      for (int j = 0; j < 4; ++j) {
        const int m = kg * 4 + j;
        const float hv = fmaxf(accH[tile][j], 0.f) + nz[tile][j];   // af = 1.0
        hs[(size_t)(b0 + m) * (LT * NH) + (size_t)t * NH + n] = hv;
        *(unsigned short*)(lds + A_S_OFF + m * 1024 + swz(m, n * 2)) = f2bf_bits(hv);
        const float rv = 0.9f * r_old[tile][j] + 0.1f * fmaxf(accR[tile][j], 0.f);
        r_old[tile][j] = rv;
        *(unsigned short*)(lds + A_S_OFF + m * 1024 + swz(m, 512 + n * 2)) = f2bf_bits(rv);
      }
    }
    if (wv == 1 && t > 0) {
#pragma unroll
      for (int j = 0; j < 4; ++j) {
        const float pv = 1.f / (1.f + __expf(-accP[j]));
        priors[(size_t)(b0 + kg * 4 + j) * (LT * 16) + (size_t)(t - 1) * 16 + col] = pv;
      }
    }

    // -------- reload accumulators / prefetch next step --------
    const int tn = (t + 1 < LT) ? (t + 1) : t;   // clamped; value unused at t=LT-1
#pragma unroll
    for (int tile = 0; tile < 4; ++tile) {       // u loads first (first consumed)
      const int n = wv * 64 + tile * 16 + col;
#pragma unroll
      for (int j = 0; j < 4; ++j)
        accH[tile][j] = hs[(size_t)(b0 + kg * 4 + j) * (LT * NH) + (size_t)tn * NH + n];
    }
#pragma unroll
    for (int tile = 0; tile < 4; ++tile) {
      const int n = wv * 64 + tile * 16 + col;
#pragma unroll
      for (int j = 0; j < 4; ++j) {
        nz[tile][j]   = noise[(size_t)tn * (BATCH * NH) + (size_t)(b0 + kg * 4 + j) * NH + n];
        accR[tile][j] = biasr[tile];
      }
    }
#pragma unroll
    for (int j = 0; j < 4; ++j) accP[j] = bpP;
    __syncthreads();   // A_s restaged for next step
  }

  // -------- tail: prior_{L-1} from staged r_{L-1} --------
  if (wv == 1) {
    f32x4 aP;
#pragma unroll
    for (int j = 0; j < 4; ++j) aP[j] = bpP;
#pragma unroll
    for (int kk8 = 0; kk8 < 8; ++kk8) {
      const bf16x8 af = *(const bf16x8*)(lds + A_S_OFF + col * 1024 +
                                         swz(col, (kk8 + 8) * 64 + kg * 16));
      const bf16x8 bp = *(const bf16x8*)(lds + W_PR_OFF + col * 512 +
                                         swz(col, kk8 * 64 + kg * 16));
      aP = __builtin_amdgcn_mfma_f32_16x16x32_bf16(af, bp, aP, 0, 0, 0);
    }
#pragma unroll
    for (int j = 0; j < 4; ++j) {
      const float pv = 1.f / (1.f + __expf(-aP[j]));
      priors[(size_t)(b0 + kg * 4 + j) * (LT * 16) + (size_t)(LT - 1) * 16 + col] = pv;
    }
  }
}

// ===================== kernel 3: out = clip(hs @ W_out^T + b_out) ==========
__global__ __launch_bounds__(256) void out_project_kernel(
    const float* __restrict__ hs,     // [B*L, 256]
    const float* __restrict__ W_out,  // [2, 256]
    const float* __restrict__ b_out,  // [2]
    float* __restrict__ outs)         // [B*L, 2]
{
  const int tid = threadIdx.x;
  const int lane = tid & 63;
  const int wv = tid >> 6;
  const int row0 = blockIdx.x * 64 + wv * 16;   // 16 rows per wave
  f32x4 w0 = *(const f32x4*)(W_out + lane * 4);
  f32x4 w1 = *(const f32x4*)(W_out + 256 + lane * 4);
  const float bo0 = b_out[0], bo1 = b_out[1];
  for (int i = 0; i < 16; ++i) {
    const f32x4 h = *(const f32x4*)(hs + (size_t)(row0 + i) * NH + lane * 4);
    float p0 = h[0]*w0[0] + h[1]*w0[1] + h[2]*w0[2] + h[3]*w0[3];
    float p1 = h[0]*w1[0] + h[1]*w1[1] + h[2]*w1[2] + h[3]*w1[3];
#pragma unroll
    for (int off = 32; off; off >>= 1) {
      p0 += __shfl_down(p0, off, 64);
      p1 += __shfl_down(p1, off, 64);
    }
    if (lane == 0) {
      const size_t o = (size_t)(row0 + i) * 2;
      outs[o]     = fminf(fmaxf(p0 + bo0, -2.f), 2.f);
      outs[o + 1] = fminf(fmaxf(p1 + bo1, -2.f), 2.f);
    }
  }
}

// ===================== launch =====================
extern "C" void kernel_launch(void* const* d_in, const int* in_sizes, int n_in,
                              void* d_out, int out_size, void* d_ws, size_t ws_size,
                              hipStream_t stream) {
  const float* x         = (const float*)d_in[0];
  const float* hidden    = (const float*)d_in[1];
  const float* reservoir = (const float*)d_in[2];
  const float* noise     = (const float*)d_in[3];
  const float* W_in      = (const float*)d_in[4];
  const float* b_in      = (const float*)d_in[5];
  const float* W_hh      = (const float*)d_in[6];
  const float* b_hh      = (const float*)d_in[7];
  const float* W_sf      = (const float*)d_in[8];
  const float* b_sf      = (const float*)d_in[9];
  const float* W_fs      = (const float*)d_in[10];
  const float* b_fs      = (const float*)d_in[11];
  const float* W_res     = (const float*)d_in[12];
  const float* b_res     = (const float*)d_in[13];
  const float* W_out     = (const float*)d_in[14];
  const float* b_out     = (const float*)d_in[15];
  const float* W_pr      = (const float*)d_in[16];
  const float* b_pr      = (const float*)d_in[17];

  float* hs     = (float*)d_out;
  float* outs   = hs + HS_ELEMS;
  float* priors = outs + OUT_ELEMS;

  // u = x@W_in^T + summed biases, written into the hs region
  u_precompute_kernel<<<2048, 256, 0, stream>>>(x, W_in, b_in, b_hh, b_sf, hs);

  // serial recurrence (4 CUs, one WG per 16 batch rows), 152KB dynamic LDS
  hipFuncSetAttribute((const void*)rnn_seq_kernel,
                      hipFuncAttributeMaxDynamicSharedMemorySize, LDS_BYTES);
  rnn_seq_kernel<<<4, 256, LDS_BYTES, stream>>>(
      hidden, reservoir, noise, W_hh, W_sf, W_fs, W_res,
      b_fs, b_res, W_pr, b_pr, hs, priors);

  // out projection from stored hs
  out_project_kernel<<<2048, 256, 0, stream>>>(hs, W_out, b_out, outs);
}

// Round 2
// 11345.069 us; speedup vs baseline: 1.1275x; 1.1275x over previous
//
#include <hip/hip_runtime.h>
#include <stdint.h>
#include <stddef.h>

// ===================== problem constants =====================
#define LT    2048
#define BATCH 64
#define NH    256
#define HS_ELEMS  (BATCH * LT * NH)   // 33554432
#define OUT_ELEMS (BATCH * LT * 2)    // 262144
// d_out layout: [hs (B,L,256) | outs (B,L,2) | priors (B,L,16)] fp32

typedef __attribute__((ext_vector_type(8))) __bf16 bf16x8;
typedef __attribute__((ext_vector_type(4))) float  f32x4;
typedef __attribute__((ext_vector_type(2))) unsigned u32x2;

// v_cvt_pk_bf16_f32: dst = {lo16: bf16(a), hi16: bf16(b)}, RNE
static __device__ __forceinline__ unsigned pk2(float a, float b) {
  unsigned r;
  asm("v_cvt_pk_bf16_f32 %0, %1, %2" : "=v"(r) : "v"(a), "v"(b));
  return r;
}
static __device__ __forceinline__ bf16x8 pack8(const float* p) {
  f32x4 a = *(const f32x4*)p;
  f32x4 b = *(const f32x4*)(p + 4);
  union { unsigned u[4]; bf16x8 v; } r;
  r.u[0] = pk2(a[0], a[1]); r.u[1] = pk2(a[2], a[3]);
  r.u[2] = pk2(b[0], b[1]); r.u[3] = pk2(b[2], b[3]);
  return r.v;
}
// XOR swizzle: flips byte-address bits 4..6 within a row
static __device__ __forceinline__ int swz(int row, int off) {
  return off ^ ((row & 7) << 4);
}

// LDS layout (bytes) for the serial kernel
#define W_RES_OFF 0        // 256 rows x 512B  (W_res[n][k] bf16, swizzled)
#define A_S_OFF   131072   // 16 rows x 1024B  (h bf16 at [0,512), r at [512,1024))
#define W_PR_OFF  147456   // 16 rows x 512B   (W_pr[n][k] bf16, swizzled)
#define LDS_BYTES 155648

// ===================== kernel 1: u = x @ W_in^T + (b_in+b_hh+b_sf) ==========
__global__ __launch_bounds__(256) void u_precompute_kernel(
    const float* __restrict__ x,      // [B, L, 16]
    const float* __restrict__ W_in,   // [256, 16]
    const float* __restrict__ b_in,
    const float* __restrict__ b_hh,
    const float* __restrict__ b_sf,
    float* __restrict__ u)            // [B, L, 256] (= hs region)
{
  __shared__ float xs[64][16];
  const int tid = threadIdx.x;
  const int b  = blockIdx.x >> 5;
  const int tc = (blockIdx.x & 31) << 6;   // 64 timesteps per block
  float w[16];
#pragma unroll
  for (int i = 0; i < 16; ++i) w[i] = W_in[tid * 16 + i];
  const float bias = b_in[tid] + b_hh[tid] + b_sf[tid];
  for (int r = tid; r < 64 * 16; r += 256)
    xs[r >> 4][r & 15] = x[((size_t)b * LT + tc + (r >> 4)) * 16 + (r & 15)];
  __syncthreads();
  for (int tt = 0; tt < 64; ++tt) {
    float s = bias;
#pragma unroll
    for (int i = 0; i < 16; ++i) s += xs[tt][i] * w[i];
    u[((size_t)b * LT + tc + tt) * NH + tid] = s;
  }
}

// ===================== kernel 2: the serial recurrence =====================
// SWAPPED MFMA roles: weights = A-operand, state = B-operand.
//   D: lane holds batch = lane&15 (= "col"), outputs n = wv*64+tile*16+kg*4+j.
// -> b64 LDS state writes, dwordx4 global load/store everywhere, cvt_pk packing.
// u prefetched 1 step ahead in regs; noise loaded 1 step ahead (epilogue use).
__global__ __launch_bounds__(256, 1) void rnn_seq_kernel(
    const float* __restrict__ hidden,     // [B,256]
    const float* __restrict__ reservoir,  // [B,256]
    const float* __restrict__ noise,      // [L,B,256]
    const float* __restrict__ W_hh, const float* __restrict__ W_sf,
    const float* __restrict__ W_fs, const float* __restrict__ W_res,
    const float* __restrict__ b_fs, const float* __restrict__ b_res,
    const float* __restrict__ W_pr, const float* __restrict__ b_pr,
    float* __restrict__ hs,               // [B,L,256] (holds u on entry)
    float* __restrict__ priors)           // [B,L,16]
{
  extern __shared__ char lds[];
  const int tid  = threadIdx.x;
  const int lane = tid & 63;
  const int wv   = tid >> 6;        // wave 0..3
  const int col  = lane & 15;       // batch row within WG / A-frag row
  const int kg   = lane >> 4;       // k-group 0..3
  const int b0   = blockIdx.x * 16;

  // ---- stage W_res into LDS: [n][k] bf16, row-swizzled, b128 writes ----
  {
    const int n = tid;
    const float* src = W_res + (size_t)n * NH;
    char* row = lds + W_RES_OFF + n * 512;
#pragma unroll 4
    for (int k = 0; k < NH; k += 8)
      *(bf16x8*)(row + swz(n, k * 2)) = pack8(src + k);
  }
  // ---- stage W_pr (16 rows) ----
  {
    const int n = tid >> 4, seg = tid & 15;
    const float* src = W_pr + (size_t)n * NH + seg * 16;
    char* row = lds + W_PR_OFF + n * 512;
    *(bf16x8*)(row + swz(n, seg * 32))      = pack8(src);
    *(bf16x8*)(row + swz(n, seg * 32 + 16)) = pack8(src + 8);
  }
  // ---- stage initial state h0, r0 into A_s ([m][k], swizzled) ----
  {
    const int m = tid >> 4, seg = tid & 15;
    const float* hsrc = hidden    + (size_t)(b0 + m) * NH + seg * 16;
    const float* rsrc = reservoir + (size_t)(b0 + m) * NH + seg * 16;
    char* row = lds + A_S_OFF + m * 1024;
    *(bf16x8*)(row + swz(m, seg * 32))            = pack8(hsrc);
    *(bf16x8*)(row + swz(m, seg * 32 + 16))       = pack8(hsrc + 8);
    *(bf16x8*)(row + swz(m, 512 + seg * 32))      = pack8(rsrc);
    *(bf16x8*)(row + swz(m, 512 + seg * 32 + 16)) = pack8(rsrc + 8);
  }

  // ---- per-lane weight fragments (A-operand; same packing as before) ----
  bf16x8 wHH[4][8], wSF[4][8], wFS[4][8];
  f32x4 biasr[4];
#pragma unroll
  for (int tile = 0; tile < 4; ++tile) {
    const int n = wv * 64 + tile * 16 + col;
#pragma unroll
    for (int kk = 0; kk < 8; ++kk) {
      wHH[tile][kk] = pack8(W_hh + (size_t)n * NH + kk * 32 + kg * 8);
      wSF[tile][kk] = pack8(W_sf + (size_t)n * NH + kk * 32 + kg * 8);
      wFS[tile][kk] = pack8(W_fs + (size_t)n * NH + kk * 32 + kg * 8);
    }
    const int nb = wv * 64 + tile * 16 + kg * 4;
    f32x4 bf = *(const f32x4*)(b_fs + nb);
    f32x4 br = *(const f32x4*)(b_res + nb);
    biasr[tile] = bf + br;
  }
  const f32x4 bp4 = *(const f32x4*)(b_pr + kg * 4);

  // ---- state / accumulators / prefetch ----
  const size_t hsRow = (size_t)(b0 + col) * (LT * NH);
  const size_t nzRow = (size_t)(b0 + col) * NH;
  f32x4 r_old[4], accH[4], accR[4], nzc[4], pfU[4], accP;
#pragma unroll
  for (int tile = 0; tile < 4; ++tile) {
    const int nb = wv * 64 + tile * 16 + kg * 4;
    r_old[tile] = *(const f32x4*)(reservoir + nzRow + nb);
    accH[tile]  = *(const f32x4*)(hs + hsRow + nb);                       // u(0)
    nzc[tile]   = *(const f32x4*)(noise + nzRow + nb);                    // nz(0)
    pfU[tile]   = *(const f32x4*)(hs + hsRow + NH + nb);                  // u(1)
    accR[tile]  = biasr[tile];
  }
  accP = bp4;

  __syncthreads();

#pragma unroll 1
  for (int t = 0; t < LT; ++t) {
    // -------- K-loop: K=512 over [h | r], 16 k-steps --------
#pragma unroll
    for (int kk = 0; kk < 16; ++kk) {
      const bf16x8 af = *(const bf16x8*)(lds + A_S_OFF + col * 1024 +
                                         swz(col, kk * 64 + kg * 16));
      if (kk < 8) {
#pragma unroll
        for (int tile = 0; tile < 4; ++tile)
          accH[tile] = __builtin_amdgcn_mfma_f32_16x16x32_bf16(wHH[tile][kk], af, accH[tile], 0, 0, 0);
#pragma unroll
        for (int tile = 0; tile < 4; ++tile)
          accR[tile] = __builtin_amdgcn_mfma_f32_16x16x32_bf16(wFS[tile][kk], af, accR[tile], 0, 0, 0);
      } else {
#pragma unroll
        for (int tile = 0; tile < 4; ++tile)
          accH[tile] = __builtin_amdgcn_mfma_f32_16x16x32_bf16(wSF[tile][kk - 8], af, accH[tile], 0, 0, 0);
#pragma unroll
        for (int tile = 0; tile < 4; ++tile) {
          const int n = wv * 64 + tile * 16 + col;
          const bf16x8 bw = *(const bf16x8*)(lds + W_RES_OFF + n * 512 +
                                             swz(n, (kk - 8) * 64 + kg * 16));
          accR[tile] = __builtin_amdgcn_mfma_f32_16x16x32_bf16(bw, af, accR[tile], 0, 0, 0);
        }
        if (wv == 1) {
          const bf16x8 bp = *(const bf16x8*)(lds + W_PR_OFF + col * 512 +
                                             swz(col, (kk - 8) * 64 + kg * 16));
          accP = __builtin_amdgcn_mfma_f32_16x16x32_bf16(bp, af, accP, 0, 0, 0);
        }
      }
    }
    __syncthreads();   // all reads of A_s done

    // -------- epilogue: update state, store h (dwordx4), restage A_s (b64) --
    float* hsT = hs + hsRow + (size_t)t * NH;
    char* rowp = lds + A_S_OFF + col * 1024;
#pragma unroll
    for (int tile = 0; tile < 4; ++tile) {
      const int nb = wv * 64 + tile * 16 + kg * 4;
      f32x4 hv, rv;
#pragma unroll
      for (int j = 0; j < 4; ++j) {
        hv[j] = fmaxf(accH[tile][j], 0.f) + nzc[tile][j];     // af = 1.0
        rv[j] = 0.9f * r_old[tile][j] + 0.1f * fmaxf(accR[tile][j], 0.f);
      }
      r_old[tile] = rv;
      *(f32x4*)(hsT + nb) = hv;
      u32x2 hp, rp;
      hp[0] = pk2(hv[0], hv[1]); hp[1] = pk2(hv[2], hv[3]);
      rp[0] = pk2(rv[0], rv[1]); rp[1] = pk2(rv[2], rv[3]);
      *(u32x2*)(rowp + swz(col, nb * 2))       = hp;
      *(u32x2*)(rowp + swz(col, 512 + nb * 2)) = rp;
    }
    if (wv == 1 && t > 0) {
      f32x4 pv;
#pragma unroll
      for (int j = 0; j < 4; ++j) pv[j] = 1.f / (1.f + __expf(-accP[j]));
      *(f32x4*)(priors + (size_t)(b0 + col) * (LT * 16) + (size_t)(t - 1) * 16 + kg * 4) = pv;
    }

    // -------- reinit accumulators + prefetch (u: t+2 into pf; nz: t+1) -----
    const size_t tp2 = (t + 2 < LT) ? (size_t)(t + 2) : (size_t)(LT - 1);
    const size_t tp1 = (t + 1 < LT) ? (size_t)(t + 1) : (size_t)(LT - 1);
#pragma unroll
    for (int tile = 0; tile < 4; ++tile) {
      const int nb = wv * 64 + tile * 16 + kg * 4;
      accH[tile] = pfU[tile];                                   // u(t+1)
      accR[tile] = biasr[tile];
      pfU[tile] = *(const f32x4*)(hs + hsRow + tp2 * NH + nb);  // u(t+2)
      nzc[tile] = *(const f32x4*)(noise + tp1 * (BATCH * NH) + nzRow + nb);
    }
    accP = bp4;
    __syncthreads();   // A_s restaged for next step
  }

  // -------- tail: prior_{L-1} from staged r_{L-1} --------
  if (wv == 1) {
    f32x4 aP = bp4;
#pragma unroll
    for (int kk8 = 0; kk8 < 8; ++kk8) {
      const bf16x8 af = *(const bf16x8*)(lds + A_S_OFF + col * 1024 +
                                         swz(col, 512 + kk8 * 64 + kg * 16));
      const bf16x8 bp = *(const bf16x8*)(lds + W_PR_OFF + col * 512 +
                                         swz(col, kk8 * 64 + kg * 16));
      aP = __builtin_amdgcn_mfma_f32_16x16x32_bf16(bp, af, aP, 0, 0, 0);
    }
    f32x4 pv;
#pragma unroll
    for (int j = 0; j < 4; ++j) pv[j] = 1.f / (1.f + __expf(-aP[j]));
    *(f32x4*)(priors + (size_t)(b0 + col) * (LT * 16) + (size_t)(LT - 1) * 16 + kg * 4) = pv;
  }
}

// ===================== kernel 3: out = clip(hs @ W_out^T + b_out) ==========
__global__ __launch_bounds__(256) void out_project_kernel(
    const float* __restrict__ hs,     // [B*L, 256]
    const float* __restrict__ W_out,  // [2, 256]
    const float* __restrict__ b_out,  // [2]
    float* __restrict__ outs)         // [B*L, 2]
{
  const int tid = threadIdx.x;
  const int lane = tid & 63;
  const int wv = tid >> 6;
  const int row0 = blockIdx.x * 64 + wv * 16;   // 16 rows per wave
  f32x4 w0 = *(const f32x4*)(W_out + lane * 4);
  f32x4 w1 = *(const f32x4*)(W_out + 256 + lane * 4);
  const float bo0 = b_out[0], bo1 = b_out[1];
  for (int i = 0; i < 16; ++i) {
    const f32x4 h = *(const f32x4*)(hs + (size_t)(row0 + i) * NH + lane * 4);
    float p0 = h[0]*w0[0] + h[1]*w0[1] + h[2]*w0[2] + h[3]*w0[3];
    float p1 = h[0]*w1[0] + h[1]*w1[1] + h[2]*w1[2] + h[3]*w1[3];
#pragma unroll
    for (int off = 32; off; off >>= 1) {
      p0 += __shfl_down(p0, off, 64);
      p1 += __shfl_down(p1, off, 64);
    }
    if (lane == 0) {
      const size_t o = (size_t)(row0 + i) * 2;
      outs[o]     = fminf(fmaxf(p0 + bo0, -2.f), 2.f);
      outs[o + 1] = fminf(fmaxf(p1 + bo1, -2.f), 2.f);
    }
  }
}

// ===================== launch =====================
extern "C" void kernel_launch(void* const* d_in, const int* in_sizes, int n_in,
                              void* d_out, int out_size, void* d_ws, size_t ws_size,
                              hipStream_t stream) {
  const float* x         = (const float*)d_in[0];
  const float* hidden    = (const float*)d_in[1];
  const float* reservoir = (const float*)d_in[2];
  const float* noise     = (const float*)d_in[3];
  const float* W_in      = (const float*)d_in[4];
  const float* b_in      = (const float*)d_in[5];
  const float* W_hh      = (const float*)d_in[6];
  const float* b_hh      = (const float*)d_in[7];
  const float* W_sf      = (const float*)d_in[8];
  const float* b_sf      = (const float*)d_in[9];
  const float* W_fs      = (const float*)d_in[10];
  const float* b_fs      = (const float*)d_in[11];
  const float* W_res     = (const float*)d_in[12];
  const float* b_res     = (const float*)d_in[13];
  const float* W_out     = (const float*)d_in[14];
  const float* b_out     = (const float*)d_in[15];
  const float* W_pr      = (const float*)d_in[16];
  const float* b_pr      = (const float*)d_in[17];

  float* hs     = (float*)d_out;
  float* outs   = hs + HS_ELEMS;
  float* priors = outs + OUT_ELEMS;

  u_precompute_kernel<<<2048, 256, 0, stream>>>(x, W_in, b_in, b_hh, b_sf, hs);

  hipFuncSetAttribute((const void*)rnn_seq_kernel,
                      hipFuncAttributeMaxDynamicSharedMemorySize, LDS_BYTES);
  rnn_seq_kernel<<<4, 256, LDS_BYTES, stream>>>(
      hidden, reservoir, noise, W_hh, W_sf, W_fs, W_res,
      b_fs, b_res, W_pr, b_pr, hs, priors);

  out_project_kernel<<<2048, 256, 0, stream>>>(hs, W_out, b_out, outs);
}

// Round 3
// 8419.272 us; speedup vs baseline: 1.5194x; 1.3475x over previous
//
#include <hip/hip_runtime.h>
#include <stdint.h>
#include <stddef.h>

// ===================== problem constants =====================
#define LT    2048
#define BATCH 64
#define NH    256
#define HS_ELEMS  (BATCH * LT * NH)   // 33554432
#define OUT_ELEMS (BATCH * LT * 2)    // 262144
// d_out layout: [hs (B,L,256) | outs (B,L,2) | priors (B,L,16)] fp32

typedef __attribute__((ext_vector_type(8))) __bf16 bf16x8;
typedef __attribute__((ext_vector_type(4))) float  f32x4;
typedef __attribute__((ext_vector_type(2))) unsigned u32x2;

// v_cvt_pk_bf16_f32: dst = {lo16: bf16(a), hi16: bf16(b)}, RNE
static __device__ __forceinline__ unsigned pk2(float a, float b) {
  unsigned r;
  asm("v_cvt_pk_bf16_f32 %0, %1, %2" : "=v"(r) : "v"(a), "v"(b));
  return r;
}
static __device__ __forceinline__ bf16x8 pack8(const float* p) {
  f32x4 a = *(const f32x4*)p;
  f32x4 b = *(const f32x4*)(p + 4);
  union { unsigned u[4]; bf16x8 v; } r;
  r.u[0] = pk2(a[0], a[1]); r.u[1] = pk2(a[2], a[3]);
  r.u[2] = pk2(b[0], b[1]); r.u[3] = pk2(b[2], b[3]);
  return r.v;
}
// XOR swizzle: flips byte-address bits 4..6 within a row
static __device__ __forceinline__ int swz(int row, int off) {
  return off ^ ((row & 7) << 4);
}

// Raw workgroup barrier: LDS ordered via lgkmcnt(0); vmcnt deliberately NOT
// drained (global prefetch loads / stores stay in flight across the barrier).
#define BARRIER() do {                                           \
    asm volatile("s_waitcnt lgkmcnt(0)" ::: "memory");           \
    __builtin_amdgcn_s_barrier();                                \
    asm volatile("" ::: "memory");                               \
  } while (0)

// LDS layout (bytes) for the serial kernel
#define W_RES_OFF 0        // 256 rows x 512B  (W_res[n][k] bf16, swizzled)
#define A_S_OFF   131072   // 16 rows x 1024B  (h bf16 at [0,512), r at [512,1024))
#define W_PR_OFF  147456   // 16 rows x 512B   (W_pr[n][k] bf16, swizzled)
#define BIAS_OFF  155648   // 64 x f32x4: (b_fs+b_res)[n] grouped by n/4
#define BP_OFF    156672   // 4 x f32x4: b_pr
#define LDS_BYTES 156736

// ===================== kernel 1: u = x @ W_in^T + (b_in+b_hh+b_sf) ==========
__global__ __launch_bounds__(256) void u_precompute_kernel(
    const float* __restrict__ x,      // [B, L, 16]
    const float* __restrict__ W_in,   // [256, 16]
    const float* __restrict__ b_in,
    const float* __restrict__ b_hh,
    const float* __restrict__ b_sf,
    float* __restrict__ u)            // [B, L, 256] (= hs region)
{
  __shared__ float xs[64][16];
  const int tid = threadIdx.x;
  const int b  = blockIdx.x >> 5;
  const int tc = (blockIdx.x & 31) << 6;   // 64 timesteps per block
  float w[16];
#pragma unroll
  for (int i = 0; i < 16; ++i) w[i] = W_in[tid * 16 + i];
  const float bias = b_in[tid] + b_hh[tid] + b_sf[tid];
  for (int r = tid; r < 64 * 16; r += 256)
    xs[r >> 4][r & 15] = x[((size_t)b * LT + tc + (r >> 4)) * 16 + (r & 15)];
  __syncthreads();
  for (int tt = 0; tt < 64; ++tt) {
    float s = bias;
#pragma unroll
    for (int i = 0; i < 16; ++i) s += xs[tt][i] * w[i];
    u[((size_t)b * LT + tc + tt) * NH + tid] = s;
  }
}

// ===================== kernel 2: the serial recurrence =====================
// 8 waves x 64 lanes; wave owns 32 output cols (2 tiles of 16) for both
// tmp_h and tmp_r. Weights = MFMA A-operand (in VGPRs), state = B-operand
// (LDS, bf16). D layout: lane&15 = batch, rows = out cols kg*4+j.
// Raw barriers: lgkmcnt-only; global prefetch (u(t+1), noise(t)) issued at
// K-loop start, consumed in the epilogue -> HBM latency hidden, never drained.
__global__ __launch_bounds__(512, 1) void rnn_seq_kernel(
    const float* __restrict__ hidden,     // [B,256]
    const float* __restrict__ reservoir,  // [B,256]
    const float* __restrict__ noise,      // [L,B,256]
    const float* __restrict__ W_hh, const float* __restrict__ W_sf,
    const float* __restrict__ W_fs, const float* __restrict__ W_res,
    const float* __restrict__ b_fs, const float* __restrict__ b_res,
    const float* __restrict__ W_pr, const float* __restrict__ b_pr,
    float* __restrict__ hs,               // [B,L,256] (holds u on entry)
    float* __restrict__ priors)           // [B,L,16]
{
  extern __shared__ char lds[];
  const int tid  = threadIdx.x;
  const int lane = tid & 63;
  const int wv   = tid >> 6;        // wave 0..7
  const int col  = lane & 15;       // batch row within WG
  const int kg   = lane >> 4;       // k-group 0..3
  const int b0   = blockIdx.x * 16;

  // ---- stage W_res into LDS: [n][k] bf16, row-swizzled; 2 threads/row ----
  {
    const int n = tid >> 1, half = tid & 1;
    const float* src = W_res + (size_t)n * NH + half * 128;
    char* row = lds + W_RES_OFF + n * 512;
#pragma unroll 4
    for (int i = 0; i < 16; ++i)
      *(bf16x8*)(row + swz(n, half * 256 + i * 16)) = pack8(src + i * 8);
  }
  // ---- stage W_pr (16 rows), threads 0..255 ----
  if (tid < 256) {
    const int n = tid >> 4, seg = tid & 15;
    const float* src = W_pr + (size_t)n * NH + seg * 16;
    char* row = lds + W_PR_OFF + n * 512;
    *(bf16x8*)(row + swz(n, seg * 32))      = pack8(src);
    *(bf16x8*)(row + swz(n, seg * 32 + 16)) = pack8(src + 8);
  }
  // ---- stage initial state h0, r0 into A_s ([m][k], swizzled) ----
  {
    const int m = tid >> 5, seg = tid & 31;   // 8 floats each
    const float* hsrc = hidden    + (size_t)(b0 + m) * NH + seg * 8;
    const float* rsrc = reservoir + (size_t)(b0 + m) * NH + seg * 8;
    char* row = lds + A_S_OFF + m * 1024;
    *(bf16x8*)(row + swz(m, seg * 16))       = pack8(hsrc);
    *(bf16x8*)(row + swz(m, 512 + seg * 16)) = pack8(rsrc);
  }
  // ---- stage biases: (b_fs+b_res) as 64 f32x4; b_pr as 4 f32x4 ----
  if (tid < 64) {
    f32x4 v = *(const f32x4*)(b_fs + tid * 4);
    f32x4 w = *(const f32x4*)(b_res + tid * 4);
    *(f32x4*)(lds + BIAS_OFF + tid * 16) = v + w;
  }
  if (tid < 4)
    *(f32x4*)(lds + BP_OFF + tid * 16) = *(const f32x4*)(b_pr + tid * 4);

  // ---- per-lane weight fragments (A-operand), 2 tiles per wave ----
  bf16x8 wHH[2][8], wSF[2][8], wFS[2][8];
#pragma unroll
  for (int tile = 0; tile < 2; ++tile) {
    const int n = wv * 32 + tile * 16 + col;
#pragma unroll
    for (int kk = 0; kk < 8; ++kk) {
      wHH[tile][kk] = pack8(W_hh + (size_t)n * NH + kk * 32 + kg * 8);
      wSF[tile][kk] = pack8(W_sf + (size_t)n * NH + kk * 32 + kg * 8);
      wFS[tile][kk] = pack8(W_fs + (size_t)n * NH + kk * 32 + kg * 8);
    }
  }

  // ---- state / accumulators ----
  const size_t hsRow = (size_t)(b0 + col) * (LT * NH);
  const size_t nzRow = (size_t)(b0 + col) * NH;
  f32x4 r_old[2], accH[2], accR[2], accP;
#pragma unroll
  for (int tile = 0; tile < 2; ++tile) {
    const int nb = wv * 32 + tile * 16 + kg * 4;
    r_old[tile] = *(const f32x4*)(reservoir + nzRow + nb);
    accH[tile]  = *(const f32x4*)(hs + hsRow + nb);                 // u(0)
    accR[tile]  = *(const f32x4*)(lds + BIAS_OFF + (nb >> 2) * 16);
  }
  accP = *(const f32x4*)(lds + BP_OFF + kg * 16);

  BARRIER();   // staging visible to all waves

#pragma unroll 1
  for (int t = 0; t < LT; ++t) {
    // ---- issue global prefetch: u(t+1) and noise(t); consumed in epilogue --
    const size_t tp1 = (t + 1 < LT) ? (size_t)(t + 1) : (size_t)(LT - 1);
    f32x4 pfU[2], nzc[2];
#pragma unroll
    for (int tile = 0; tile < 2; ++tile) {
      const int nb = wv * 32 + tile * 16 + kg * 4;
      pfU[tile] = *(const f32x4*)(hs + hsRow + tp1 * NH + nb);
      nzc[tile] = *(const f32x4*)(noise + (size_t)t * (BATCH * NH) + nzRow + nb);
    }

    // -------- K-loop: K=512 over [h | r], 16 k-steps --------
#pragma unroll
    for (int kk = 0; kk < 16; ++kk) {
      const bf16x8 af = *(const bf16x8*)(lds + A_S_OFF + col * 1024 +
                                         swz(col, kk * 64 + kg * 16));
      if (kk < 8) {
#pragma unroll
        for (int tile = 0; tile < 2; ++tile)
          accH[tile] = __builtin_amdgcn_mfma_f32_16x16x32_bf16(wHH[tile][kk], af, accH[tile], 0, 0, 0);
#pragma unroll
        for (int tile = 0; tile < 2; ++tile)
          accR[tile] = __builtin_amdgcn_mfma_f32_16x16x32_bf16(wFS[tile][kk], af, accR[tile], 0, 0, 0);
      } else {
#pragma unroll
        for (int tile = 0; tile < 2; ++tile)
          accH[tile] = __builtin_amdgcn_mfma_f32_16x16x32_bf16(wSF[tile][kk - 8], af, accH[tile], 0, 0, 0);
#pragma unroll
        for (int tile = 0; tile < 2; ++tile) {
          const int n = wv * 32 + tile * 16 + col;
          const bf16x8 bw = *(const bf16x8*)(lds + W_RES_OFF + n * 512 +
                                             swz(n, (kk - 8) * 64 + kg * 16));
          accR[tile] = __builtin_amdgcn_mfma_f32_16x16x32_bf16(bw, af, accR[tile], 0, 0, 0);
        }
        if (wv == 1) {
          const bf16x8 bp = *(const bf16x8*)(lds + W_PR_OFF + col * 512 +
                                             swz(col, (kk - 8) * 64 + kg * 16));
          accP = __builtin_amdgcn_mfma_f32_16x16x32_bf16(bp, af, accP, 0, 0, 0);
        }
      }
    }
    BARRIER();   // all reads of A_s done before overwrite (no vmcnt drain)

    // -------- epilogue: update state, store h, restage A_s --------
    float* hsT = hs + hsRow + (size_t)t * NH;
    char* rowp = lds + A_S_OFF + col * 1024;
#pragma unroll
    for (int tile = 0; tile < 2; ++tile) {
      const int nb = wv * 32 + tile * 16 + kg * 4;
      f32x4 hv, rv;
#pragma unroll
      for (int j = 0; j < 4; ++j) {
        hv[j] = fmaxf(accH[tile][j], 0.f) + nzc[tile][j];     // alpha_fast = 1
        rv[j] = 0.9f * r_old[tile][j] + 0.1f * fmaxf(accR[tile][j], 0.f);
      }
      r_old[tile] = rv;
      *(f32x4*)(hsT + nb) = hv;
      u32x2 hp, rp;
      hp[0] = pk2(hv[0], hv[1]); hp[1] = pk2(hv[2], hv[3]);
      rp[0] = pk2(rv[0], rv[1]); rp[1] = pk2(rv[2], rv[3]);
      *(u32x2*)(rowp + swz(col, nb * 2))       = hp;
      *(u32x2*)(rowp + swz(col, 512 + nb * 2)) = rp;
    }
    if (wv == 1 && t > 0) {
      f32x4 pv;
#pragma unroll
      for (int j = 0; j < 4; ++j) pv[j] = 1.f / (1.f + __expf(-accP[j]));
      *(f32x4*)(priors + (size_t)(b0 + col) * (LT * 16) + (size_t)(t - 1) * 16 + kg * 4) = pv;
    }

    // -------- reinit accumulators for next step --------
#pragma unroll
    for (int tile = 0; tile < 2; ++tile) {
      const int nb = wv * 32 + tile * 16 + kg * 4;
      accH[tile] = pfU[tile];                                   // u(t+1)
      accR[tile] = *(const f32x4*)(lds + BIAS_OFF + (nb >> 2) * 16);
    }
    accP = *(const f32x4*)(lds + BP_OFF + kg * 16);
    BARRIER();   // A_s restaged for next step (no vmcnt drain)
  }

  // -------- tail: prior_{L-1} from staged r_{L-1} --------
  if (wv == 1) {
    f32x4 aP = *(const f32x4*)(lds + BP_OFF + kg * 16);
#pragma unroll
    for (int kk8 = 0; kk8 < 8; ++kk8) {
      const bf16x8 af = *(const bf16x8*)(lds + A_S_OFF + col * 1024 +
                                         swz(col, 512 + kk8 * 64 + kg * 16));
      const bf16x8 bp = *(const bf16x8*)(lds + W_PR_OFF + col * 512 +
                                         swz(col, kk8 * 64 + kg * 16));
      aP = __builtin_amdgcn_mfma_f32_16x16x32_bf16(bp, af, aP, 0, 0, 0);
    }
    f32x4 pv;
#pragma unroll
    for (int j = 0; j < 4; ++j) pv[j] = 1.f / (1.f + __expf(-aP[j]));
    *(f32x4*)(priors + (size_t)(b0 + col) * (LT * 16) + (size_t)(LT - 1) * 16 + kg * 4) = pv;
  }
}

// ===================== kernel 3: out = clip(hs @ W_out^T + b_out) ==========
__global__ __launch_bounds__(256) void out_project_kernel(
    const float* __restrict__ hs,     // [B*L, 256]
    const float* __restrict__ W_out,  // [2, 256]
    const float* __restrict__ b_out,  // [2]
    float* __restrict__ outs)         // [B*L, 2]
{
  const int tid = threadIdx.x;
  const int lane = tid & 63;
  const int wv = tid >> 6;
  const int row0 = blockIdx.x * 64 + wv * 16;   // 16 rows per wave
  f32x4 w0 = *(const f32x4*)(W_out + lane * 4);
  f32x4 w1 = *(const f32x4*)(W_out + 256 + lane * 4);
  const float bo0 = b_out[0], bo1 = b_out[1];
  for (int i = 0; i < 16; ++i) {
    const f32x4 h = *(const f32x4*)(hs + (size_t)(row0 + i) * NH + lane * 4);
    float p0 = h[0]*w0[0] + h[1]*w0[1] + h[2]*w0[2] + h[3]*w0[3];
    float p1 = h[0]*w1[0] + h[1]*w1[1] + h[2]*w1[2] + h[3]*w1[3];
#pragma unroll
    for (int off = 32; off; off >>= 1) {
      p0 += __shfl_down(p0, off, 64);
      p1 += __shfl_down(p1, off, 64);
    }
    if (lane == 0) {
      const size_t o = (size_t)(row0 + i) * 2;
      outs[o]     = fminf(fmaxf(p0 + bo0, -2.f), 2.f);
      outs[o + 1] = fminf(fmaxf(p1 + bo1, -2.f), 2.f);
    }
  }
}

// ===================== launch =====================
extern "C" void kernel_launch(void* const* d_in, const int* in_sizes, int n_in,
                              void* d_out, int out_size, void* d_ws, size_t ws_size,
                              hipStream_t stream) {
  const float* x         = (const float*)d_in[0];
  const float* hidden    = (const float*)d_in[1];
  const float* reservoir = (const float*)d_in[2];
  const float* noise     = (const float*)d_in[3];
  const float* W_in      = (const float*)d_in[4];
  const float* b_in      = (const float*)d_in[5];
  const float* W_hh      = (const float*)d_in[6];
  const float* b_hh      = (const float*)d_in[7];
  const float* W_sf      = (const float*)d_in[8];
  const float* b_sf      = (const float*)d_in[9];
  const float* W_fs      = (const float*)d_in[10];
  const float* b_fs      = (const float*)d_in[11];
  const float* W_res     = (const float*)d_in[12];
  const float* b_res     = (const float*)d_in[13];
  const float* W_out     = (const float*)d_in[14];
  const float* b_out     = (const float*)d_in[15];
  const float* W_pr      = (const float*)d_in[16];
  const float* b_pr      = (const float*)d_in[17];

  float* hs     = (float*)d_out;
  float* outs   = hs + HS_ELEMS;
  float* priors = outs + OUT_ELEMS;

  u_precompute_kernel<<<2048, 256, 0, stream>>>(x, W_in, b_in, b_hh, b_sf, hs);

  hipFuncSetAttribute((const void*)rnn_seq_kernel,
                      hipFuncAttributeMaxDynamicSharedMemorySize, LDS_BYTES);
  rnn_seq_kernel<<<4, 512, LDS_BYTES, stream>>>(
      hidden, reservoir, noise, W_hh, W_sf, W_fs, W_res,
      b_fs, b_res, W_pr, b_pr, hs, priors);

  out_project_kernel<<<2048, 256, 0, stream>>>(hs, W_out, b_out, outs);
}